// Round 1
// baseline (178.008 us; speedup 1.0000x reference)
//
#include <hip/hip_runtime.h>

#define EN 2048
#define SN 256
#define QN 25
#define NNODES 36
#define RN 15
#define HN 128

typedef __attribute__((ext_vector_type(8))) short short8;
typedef __attribute__((ext_vector_type(4))) float f32x4;
typedef __attribute__((ext_vector_type(2))) unsigned int uint2v;

__device__ __forceinline__ unsigned short f2bf(float f) {
    unsigned int u = __float_as_uint(f);
    u += 0x7fffu + ((u >> 16) & 1u);   // round-to-nearest-even
    return (unsigned short)(u >> 16);
}
__device__ __forceinline__ float bf2f(unsigned short h) {
    return __uint_as_float(((unsigned int)h) << 16);
}
// tanh(x) = 1 - 2/(exp2(2x*log2e)+1); v_exp + v_rcp, ~1e-6 rel err
__device__ __forceinline__ float fast_tanh(float x) {
    float xs = x * 2.885390082f;
    xs = fminf(fmaxf(xs, -60.f), 60.f);
    float e = __builtin_amdgcn_exp2f(xs);
    float r = __builtin_amdgcn_rcpf(e + 1.f);
    return fmaf(-2.f, r, 1.f);
}

__global__ void zero_kernel(float* __restrict__ out) {
    if (threadIdx.x == 0) out[0] = 0.f;
}

// ---------------- Mc[s][r][c] = sum_q w[q]*Base[q][r]*{Ixx|Iyy}[s][q][n] ----
__global__ __launch_bounds__(256)
void mc_kernel(const float* __restrict__ Ixx, const float* __restrict__ Iyy,
               const float* __restrict__ wq, const float* __restrict__ Base,
               float* __restrict__ Mc)
{
    __shared__ float WB[QN * 16];
    const int t = threadIdx.x;
    for (int i = t; i < QN * 16; i += 256) {
        const int q = i >> 4, r = i & 15;
        if (r < RN) WB[i] = wq[q] * Base[q * RN + r];
    }
    __syncthreads();
    const int o = blockIdx.x * 256 + t;          // grid covers 276480 exactly
    const int c  = o % 72;
    const int sr = o / 72;
    const int r  = sr % RN;
    const int s  = sr / RN;
    const float* __restrict__ I = (c < NNODES) ? Ixx : Iyy;
    const int n = (c < NNODES) ? c : (c - NNODES);
    float a0 = 0.f, a1 = 0.f;
    #pragma unroll
    for (int q = 0; q < QN - 1; q += 2) {
        a0 = fmaf(WB[q * 16 + r],       I[(s * QN + q) * NNODES + n],       a0);
        a1 = fmaf(WB[(q + 1) * 16 + r], I[(s * QN + q + 1) * NNODES + n],   a1);
    }
    a0 = fmaf(WB[(QN - 1) * 16 + r], I[(s * QN + QN - 1) * NNODES + n], a0);
    Mc[o] = a0 + a1;
}

// ---------------- MLP: fused 4-layer net, bf16 MFMA hidden layers ----------
__device__ __forceinline__ void load_W(const float* __restrict__ W,
                                       unsigned short (*Ws)[136], int t)
{
    // Ws[n][k] = bf16(W[k][n])  (transposed, for B-operand fragments)
    const int n = t & 127;
    const int h = t >> 7;
    #pragma unroll
    for (int kk = 0; kk < 16; kk++) {
        const int k0 = (kk * 2 + h) * 4;
        const float a0 = W[(k0 + 0) * HN + n];
        const float a1 = W[(k0 + 1) * HN + n];
        const float a2 = W[(k0 + 2) * HN + n];
        const float a3 = W[(k0 + 3) * HN + n];
        uint2v pk;
        pk[0] = (unsigned)f2bf(a0) | ((unsigned)f2bf(a1) << 16);
        pk[1] = (unsigned)f2bf(a2) | ((unsigned)f2bf(a3) << 16);
        *(uint2v*)&Ws[n][k0] = pk;
    }
}

__device__ __forceinline__ void mfma_layer(unsigned short (*Hs)[136],
                                           const unsigned short (*Ws)[136],
                                           const float* __restrict__ bias,
                                           int wv, int rowA, int quad)
{
    const int r0 = wv * 32;               // wave owns 32 rows: no barriers needed
    short8 afrag[2][4];
    #pragma unroll
    for (int rt = 0; rt < 2; rt++)
        #pragma unroll
        for (int kt = 0; kt < 4; kt++)
            afrag[rt][kt] = *(const short8*)&Hs[r0 + rt * 16 + rowA][kt * 32 + quad * 8];

    f32x4 acc[2][8];
    const f32x4 zero = {0.f, 0.f, 0.f, 0.f};
    #pragma unroll
    for (int rt = 0; rt < 2; rt++)
        #pragma unroll
        for (int nt = 0; nt < 8; nt++) acc[rt][nt] = zero;

    #pragma unroll
    for (int nt = 0; nt < 8; nt++) {
        #pragma unroll
        for (int kt = 0; kt < 4; kt++) {
            const short8 bfrag = *(const short8*)&Ws[nt * 16 + rowA][kt * 32 + quad * 8];
            acc[0][nt] = __builtin_amdgcn_mfma_f32_16x16x32_bf16(afrag[0][kt], bfrag, acc[0][nt], 0, 0, 0);
            acc[1][nt] = __builtin_amdgcn_mfma_f32_16x16x32_bf16(afrag[1][kt], bfrag, acc[1][nt], 0, 0, 0);
        }
    }
    // epilogue: bias + tanh, bf16 back to Hs in place (own rows only)
    #pragma unroll
    for (int nt = 0; nt < 8; nt++) {
        const int col = nt * 16 + rowA;
        const float bv = bias[col];
        #pragma unroll
        for (int rt = 0; rt < 2; rt++) {
            #pragma unroll
            for (int rg = 0; rg < 4; rg++) {
                const float v = fast_tanh(acc[rt][nt][rg] + bv);
                Hs[r0 + rt * 16 + quad * 4 + rg][col] = f2bf(v);
            }
        }
    }
}

__global__ __launch_bounds__(256, 2)
void mlp_kernel(const float* __restrict__ nodes,
                const float* __restrict__ W1, const float* __restrict__ b1,
                const float* __restrict__ W2, const float* __restrict__ b2,
                const float* __restrict__ W3, const float* __restrict__ b3,
                const float* __restrict__ W4, const float* __restrict__ b4,
                const float* __restrict__ B_DD,
                float* __restrict__ evc)
{
    __shared__ unsigned short Hs[128][136];   // 128 points x 128 hidden, +8 pad
    __shared__ unsigned short Ws[128][136];   // W^T bf16
    const int t    = threadIdx.x;
    const int lane = t & 63;
    const int wv   = t >> 6;
    const int rowA = lane & 15;
    const int quad = lane >> 4;

    // layer 1: h1 = tanh(x @ W1 + b1)
    {
        const int p  = t >> 1;
        const int P  = blockIdx.x * 128 + p;
        const float x0 = nodes[2 * P], x1 = nodes[2 * P + 1];
        const int n0 = (t & 1) * 64;
        #pragma unroll
        for (int i = 0; i < 16; i++) {
            const int n = n0 + 4 * i;
            const float4 wa = *(const float4*)(W1 + n);
            const float4 wb = *(const float4*)(W1 + HN + n);
            const float4 bb = *(const float4*)(b1 + n);
            const float h0 = fast_tanh(fmaf(x0, wa.x, fmaf(x1, wb.x, bb.x)));
            const float h1 = fast_tanh(fmaf(x0, wa.y, fmaf(x1, wb.y, bb.y)));
            const float h2 = fast_tanh(fmaf(x0, wa.z, fmaf(x1, wb.z, bb.z)));
            const float h3 = fast_tanh(fmaf(x0, wa.w, fmaf(x1, wb.w, bb.w)));
            uint2v pk;
            pk[0] = (unsigned)f2bf(h0) | ((unsigned)f2bf(h1) << 16);
            pk[1] = (unsigned)f2bf(h2) | ((unsigned)f2bf(h3) << 16);
            *(uint2v*)&Hs[p][n] = pk;
        }
    }
    load_W(W2, Ws, t);
    __syncthreads();
    mfma_layer(Hs, Ws, b2, wv, rowA, quad);
    __syncthreads();                      // all waves done reading W2
    load_W(W3, Ws, t);
    __syncthreads();
    mfma_layer(Hs, Ws, b3, wv, rowA, quad);
    // layer 4 + evc epilogue (wave reads only its own rows: no barrier)
    {
        const int p  = t >> 1;
        const int k0 = (t & 1) * 64;
        float d = 0.f;
        #pragma unroll
        for (int i = 0; i < 8; i++) {
            const short8 h = *(const short8*)&Hs[p][k0 + 8 * i];
            const float4 wA = *(const float4*)(W4 + k0 + 8 * i);
            const float4 wB = *(const float4*)(W4 + k0 + 8 * i + 4);
            d = fmaf(bf2f((unsigned short)h[0]), wA.x, d);
            d = fmaf(bf2f((unsigned short)h[1]), wA.y, d);
            d = fmaf(bf2f((unsigned short)h[2]), wA.z, d);
            d = fmaf(bf2f((unsigned short)h[3]), wA.w, d);
            d = fmaf(bf2f((unsigned short)h[4]), wB.x, d);
            d = fmaf(bf2f((unsigned short)h[5]), wB.y, d);
            d = fmaf(bf2f((unsigned short)h[6]), wB.z, d);
            d = fmaf(bf2f((unsigned short)h[7]), wB.w, d);
        }
        d += __shfl_xor(d, 1, 64);
        if ((t & 1) == 0) {
            const float ev = d + b4[0];
            const int P  = blockIdx.x * 128 + p;
            const int e  = P / NNODES;
            const int ne = P - e * NNODES;
            const float c0 = B_DD[4 * e + 0] + B_DD[4 * e + 2];
            const float c1 = B_DD[4 * e + 1] + B_DD[4 * e + 3];
            evc[e * 72 + ne]      = c0 * ev;
            evc[e * 72 + 36 + ne] = c1 * ev;
        }
    }
}

// ---------------- loss: sum_{e,s} mean_r (-J*dot(Mc,evc) - F)^2 ------------
__global__ __launch_bounds__(256, 2)
void loss_kernel(const float* __restrict__ Mc, const float* __restrict__ evcg,
                 const float* __restrict__ J, const float* __restrict__ F,
                 float* __restrict__ out)
{
    const int t    = threadIdx.x;
    const int lane = t & 63;
    const int wv   = t >> 6;
    const int e0 = (blockIdx.x & 31) * 64;        // 32 e-blocks
    const int s0 = (blockIdx.x >> 5) * 4;         // 64 s-blocks
    const int e = e0 + lane;
    const int s = __builtin_amdgcn_readfirstlane(s0 + wv);  // wave-uniform

    float evr[72];
    const float4* ep = (const float4*)(evcg + e * 72);
    #pragma unroll
    for (int i = 0; i < 18; i++) {
        const float4 v = ep[i];
        evr[4 * i + 0] = v.x; evr[4 * i + 1] = v.y;
        evr[4 * i + 2] = v.z; evr[4 * i + 3] = v.w;
    }
    const float Jv = J[e * SN + s];
    const float* __restrict__ Fp = F + (e * SN + s) * RN;
    float Fv[RN];
    #pragma unroll
    for (int r = 0; r < RN; r++) Fv[r] = Fp[r];

    const float* __restrict__ Mb = Mc + s * (RN * 72);
    float acc = 0.f;
    for (int r = 0; r < RN; r++) {
        const float* __restrict__ Mr = Mb + r * 72;  // uniform -> s_load bcast
        float d0 = 0.f, d1 = 0.f, d2 = 0.f, d3 = 0.f;
        #pragma unroll
        for (int n = 0; n < 72; n += 4) {
            d0 = fmaf(Mr[n + 0], evr[n + 0], d0);
            d1 = fmaf(Mr[n + 1], evr[n + 1], d1);
            d2 = fmaf(Mr[n + 2], evr[n + 2], d2);
            d3 = fmaf(Mr[n + 3], evr[n + 3], d3);
        }
        const float d = (d0 + d1) + (d2 + d3);
        const float res = fmaf(-Jv, d, -Fv[r]);
        acc = fmaf(res, res, acc);
    }
    acc *= (1.f / (float)RN);
    #pragma unroll
    for (int off = 32; off > 0; off >>= 1)
        acc += __shfl_down(acc, off, 64);
    __shared__ float wsum[4];
    if (lane == 0) wsum[wv] = acc;
    __syncthreads();
    if (t == 0) atomicAdd(out, (wsum[0] + wsum[1]) + (wsum[2] + wsum[3]));
}

extern "C" void kernel_launch(void* const* d_in, const int* in_sizes, int n_in,
                              void* d_out, int out_size, void* d_ws, size_t ws_size,
                              hipStream_t stream)
{
    (void)in_sizes; (void)n_in; (void)out_size; (void)ws_size;
    const float* nodes = (const float*)d_in[0];
    const float* W1   = (const float*)d_in[1];
    const float* b1   = (const float*)d_in[2];
    const float* W2   = (const float*)d_in[3];
    const float* b2   = (const float*)d_in[4];
    const float* W3   = (const float*)d_in[5];
    const float* b3   = (const float*)d_in[6];
    const float* W4   = (const float*)d_in[7];
    const float* b4   = (const float*)d_in[8];
    const float* Ixx  = (const float*)d_in[9];
    const float* Iyy  = (const float*)d_in[10];
    const float* B_DD = (const float*)d_in[11];
    const float* wq   = (const float*)d_in[12];
    const float* Base = (const float*)d_in[13];
    const float* J    = (const float*)d_in[14];
    const float* F    = (const float*)d_in[15];
    float* out = (float*)d_out;
    float* evc = (float*)d_ws;                                   // 2048*72 f32
    float* Mc  = (float*)((char*)d_ws + EN * 72 * sizeof(float)); // 256*15*72 f32

    zero_kernel<<<1, 64, 0, stream>>>(out);
    mc_kernel<<<1080, 256, 0, stream>>>(Ixx, Iyy, wq, Base, Mc);
    mlp_kernel<<<576, 256, 0, stream>>>(nodes, W1, b1, W2, b2, W3, b3, W4, b4, B_DD, evc);
    loss_kernel<<<2048, 256, 0, stream>>>(Mc, evc, J, F, out);
}

// Round 2
// 172.606 us; speedup vs baseline: 1.0313x; 1.0313x over previous
//
#include <hip/hip_runtime.h>

#define EN 2048
#define SN 256
#define QN 25
#define NNODES 36
#define RN 15
#define HN 128

typedef __attribute__((ext_vector_type(8))) short short8;
typedef __attribute__((ext_vector_type(4))) float f32x4;
typedef __attribute__((ext_vector_type(2))) unsigned int uint2v;

__device__ __forceinline__ unsigned short f2bf(float f) {
    unsigned int u = __float_as_uint(f);
    u += 0x7fffu + ((u >> 16) & 1u);   // round-to-nearest-even
    return (unsigned short)(u >> 16);
}
__device__ __forceinline__ float bf2f(unsigned short h) {
    return __uint_as_float(((unsigned int)h) << 16);
}
// tanh(x) = 1 - 2/(exp2(2x*log2e)+1)
__device__ __forceinline__ float fast_tanh(float x) {
    float xs = x * 2.885390082f;
    xs = fminf(fmaxf(xs, -60.f), 60.f);
    float e = __builtin_amdgcn_exp2f(xs);
    float r = __builtin_amdgcn_rcpf(e + 1.f);
    return fmaf(-2.f, r, 1.f);
}

// ---------------- MLP helpers (unchanged math from R1 — validated) ---------
__device__ __forceinline__ void load_W(const float* __restrict__ W,
                                       unsigned short (*Ws)[136], int t)
{
    const int n = t & 127;
    const int h = t >> 7;
    #pragma unroll
    for (int kk = 0; kk < 16; kk++) {
        const int k0 = (kk * 2 + h) * 4;
        const float a0 = W[(k0 + 0) * HN + n];
        const float a1 = W[(k0 + 1) * HN + n];
        const float a2 = W[(k0 + 2) * HN + n];
        const float a3 = W[(k0 + 3) * HN + n];
        uint2v pk;
        pk[0] = (unsigned)f2bf(a0) | ((unsigned)f2bf(a1) << 16);
        pk[1] = (unsigned)f2bf(a2) | ((unsigned)f2bf(a3) << 16);
        *(uint2v*)&Ws[n][k0] = pk;
    }
}

__device__ __forceinline__ void mfma_layer(unsigned short (*Hs)[136],
                                           const unsigned short (*Ws)[136],
                                           const float* __restrict__ bias,
                                           int wv, int rowA, int quad)
{
    const int r0 = wv * 32;               // wave owns 32 rows: no barriers needed
    short8 afrag[2][4];
    #pragma unroll
    for (int rt = 0; rt < 2; rt++)
        #pragma unroll
        for (int kt = 0; kt < 4; kt++)
            afrag[rt][kt] = *(const short8*)&Hs[r0 + rt * 16 + rowA][kt * 32 + quad * 8];

    f32x4 acc[2][8];
    const f32x4 zero = {0.f, 0.f, 0.f, 0.f};
    #pragma unroll
    for (int rt = 0; rt < 2; rt++)
        #pragma unroll
        for (int nt = 0; nt < 8; nt++) acc[rt][nt] = zero;

    #pragma unroll
    for (int nt = 0; nt < 8; nt++) {
        #pragma unroll
        for (int kt = 0; kt < 4; kt++) {
            const short8 bfrag = *(const short8*)&Ws[nt * 16 + rowA][kt * 32 + quad * 8];
            acc[0][nt] = __builtin_amdgcn_mfma_f32_16x16x32_bf16(afrag[0][kt], bfrag, acc[0][nt], 0, 0, 0);
            acc[1][nt] = __builtin_amdgcn_mfma_f32_16x16x32_bf16(afrag[1][kt], bfrag, acc[1][nt], 0, 0, 0);
        }
    }
    #pragma unroll
    for (int nt = 0; nt < 8; nt++) {
        const int col = nt * 16 + rowA;
        const float bv = bias[col];
        #pragma unroll
        for (int rt = 0; rt < 2; rt++) {
            #pragma unroll
            for (int rg = 0; rg < 4; rg++) {
                const float v = fast_tanh(acc[rt][nt][rg] + bv);
                Hs[r0 + rt * 16 + quad * 4 + rg][col] = f2bf(v);
            }
        }
    }
}

// ---------------- fused prep: out-zero + Mc precompute + MLP ---------------
#define MLP_BLOCKS 576
#define MC_BLOCKS 1080

__global__ __launch_bounds__(256, 2)
void prep_kernel(const float* __restrict__ nodes,
                 const float* __restrict__ W1, const float* __restrict__ b1,
                 const float* __restrict__ W2, const float* __restrict__ b2,
                 const float* __restrict__ W3, const float* __restrict__ b3,
                 const float* __restrict__ W4, const float* __restrict__ b4,
                 const float* __restrict__ B_DD,
                 const float* __restrict__ Ixx, const float* __restrict__ Iyy,
                 const float* __restrict__ wq, const float* __restrict__ Base,
                 float* __restrict__ evc, float* __restrict__ Mc,
                 float* __restrict__ out)
{
    __shared__ unsigned short Hs[128][136];
    __shared__ unsigned short Ws[128][136];
    __shared__ float WB[QN * 16];
    const int bid = blockIdx.x;
    const int t   = threadIdx.x;

    if (bid < MLP_BLOCKS) {
        // =========================== MLP part ===========================
        const int lane = t & 63;
        const int wv   = t >> 6;
        const int rowA = lane & 15;
        const int quad = lane >> 4;

        // layer 1
        {
            const int p  = t >> 1;
            const int P  = bid * 128 + p;
            const float x0 = nodes[2 * P], x1 = nodes[2 * P + 1];
            const int n0 = (t & 1) * 64;
            #pragma unroll
            for (int i = 0; i < 16; i++) {
                const int n = n0 + 4 * i;
                const float4 wa = *(const float4*)(W1 + n);
                const float4 wb = *(const float4*)(W1 + HN + n);
                const float4 bb = *(const float4*)(b1 + n);
                const float h0 = fast_tanh(fmaf(x0, wa.x, fmaf(x1, wb.x, bb.x)));
                const float h1 = fast_tanh(fmaf(x0, wa.y, fmaf(x1, wb.y, bb.y)));
                const float h2 = fast_tanh(fmaf(x0, wa.z, fmaf(x1, wb.z, bb.z)));
                const float h3 = fast_tanh(fmaf(x0, wa.w, fmaf(x1, wb.w, bb.w)));
                uint2v pk;
                pk[0] = (unsigned)f2bf(h0) | ((unsigned)f2bf(h1) << 16);
                pk[1] = (unsigned)f2bf(h2) | ((unsigned)f2bf(h3) << 16);
                *(uint2v*)&Hs[p][n] = pk;
            }
        }
        load_W(W2, Ws, t);
        __syncthreads();
        mfma_layer(Hs, Ws, b2, wv, rowA, quad);
        __syncthreads();
        load_W(W3, Ws, t);
        __syncthreads();
        mfma_layer(Hs, Ws, b3, wv, rowA, quad);
        // layer 4 + evc epilogue
        {
            const int p  = t >> 1;
            const int k0 = (t & 1) * 64;
            float d = 0.f;
            #pragma unroll
            for (int i = 0; i < 8; i++) {
                const short8 h = *(const short8*)&Hs[p][k0 + 8 * i];
                const float4 wA = *(const float4*)(W4 + k0 + 8 * i);
                const float4 wB = *(const float4*)(W4 + k0 + 8 * i + 4);
                d = fmaf(bf2f((unsigned short)h[0]), wA.x, d);
                d = fmaf(bf2f((unsigned short)h[1]), wA.y, d);
                d = fmaf(bf2f((unsigned short)h[2]), wA.z, d);
                d = fmaf(bf2f((unsigned short)h[3]), wA.w, d);
                d = fmaf(bf2f((unsigned short)h[4]), wB.x, d);
                d = fmaf(bf2f((unsigned short)h[5]), wB.y, d);
                d = fmaf(bf2f((unsigned short)h[6]), wB.z, d);
                d = fmaf(bf2f((unsigned short)h[7]), wB.w, d);
            }
            d += __shfl_xor(d, 1, 64);
            if ((t & 1) == 0) {
                const float ev = d + b4[0];
                const int P  = bid * 128 + p;
                const int e  = P / NNODES;
                const int ne = P - e * NNODES;
                const float c0 = B_DD[4 * e + 0] + B_DD[4 * e + 2];
                const float c1 = B_DD[4 * e + 1] + B_DD[4 * e + 3];
                evc[e * 72 + ne]      = c0 * ev;
                evc[e * 72 + 36 + ne] = c1 * ev;
            }
        }
    } else {
        // =========================== Mc part ============================
        if (bid == MLP_BLOCKS && t == 0) out[0] = 0.f;
        for (int i = t; i < QN * 16; i += 256) {
            const int q = i >> 4, r = i & 15;
            if (r < RN) WB[i] = wq[q] * Base[q * RN + r];
        }
        __syncthreads();
        const int o = (bid - MLP_BLOCKS) * 256 + t;   // covers 276480 exactly
        const int c  = o % 72;
        const int sr = o / 72;
        const int r  = sr % RN;
        const int s  = sr / RN;
        const float* __restrict__ I = (c < NNODES) ? Ixx : Iyy;
        const int n = (c < NNODES) ? c : (c - NNODES);
        float a0 = 0.f, a1 = 0.f;
        #pragma unroll
        for (int q = 0; q < QN - 1; q += 2) {
            a0 = fmaf(WB[q * 16 + r],       I[(s * QN + q) * NNODES + n],     a0);
            a1 = fmaf(WB[(q + 1) * 16 + r], I[(s * QN + q + 1) * NNODES + n], a1);
        }
        a0 = fmaf(WB[(QN - 1) * 16 + r], I[(s * QN + QN - 1) * NNODES + n], a0);
        Mc[o] = a0 + a1;
    }
}

// ---------------- loss: Mc row in VGPRs, evc via scalar loads --------------
// thread -> (s, r): r = t&15 (15 active), s = (bid&15)*16 + (t>>4)
// block loops over 16 e values (uniform) -> evc[e][:] scalar-loaded (SGPR ops)
__global__ __launch_bounds__(256, 4)
void loss_kernel(const float* __restrict__ Mc, const float* __restrict__ evcg,
                 const float* __restrict__ J, const float* __restrict__ F,
                 float* __restrict__ out)
{
    const int t  = threadIdx.x;
    const int r  = t & 15;
    const int s  = (blockIdx.x & 15) * 16 + (t >> 4);
    const int e0 = (int)(blockIdx.x >> 4) * 16;          // 128 e-blocks
    const int rr = (r < RN) ? r : (RN - 1);
    const float vmask = (r < RN) ? 1.f : 0.f;

    // Mc row -> 72 VGPRs, reused across 16 e
    float mc[72];
    {
        const float4* __restrict__ mp = (const float4*)(Mc + ((size_t)s * RN + rr) * 72);
        #pragma unroll
        for (int i = 0; i < 18; i++) {
            const float4 v = mp[i];
            mc[4*i+0] = v.x; mc[4*i+1] = v.y; mc[4*i+2] = v.z; mc[4*i+3] = v.w;
        }
    }

    const float* __restrict__ Jp = J + (size_t)e0 * SN + s;
    const float* __restrict__ Fp = F + ((size_t)e0 * SN + s) * RN + rr;
    const float* __restrict__ ev = evcg + (size_t)e0 * 72;   // uniform pointer

    float acc = 0.f;
    #pragma unroll 1
    for (int ei = 0; ei < 16; ei++) {
        const float Jv = *Jp;
        const float Fv = *Fp;
        float d0 = 0.f, d1 = 0.f, d2 = 0.f, d3 = 0.f;
        #pragma unroll
        for (int n = 0; n < 72; n += 4) {
            d0 = fmaf(ev[n + 0], mc[n + 0], d0);
            d1 = fmaf(ev[n + 1], mc[n + 1], d1);
            d2 = fmaf(ev[n + 2], mc[n + 2], d2);
            d3 = fmaf(ev[n + 3], mc[n + 3], d3);
        }
        const float d = (d0 + d1) + (d2 + d3);
        float res = fmaf(-Jv, d, -Fv);
        res *= vmask;
        acc = fmaf(res, res, acc);
        Jp += SN;
        Fp += SN * RN;
        ev += 72;
    }
    acc *= (1.f / (float)RN);

    #pragma unroll
    for (int off = 32; off; off >>= 1)
        acc += __shfl_down(acc, off, 64);
    __shared__ float wsum[4];
    const int lane = t & 63, wv = t >> 6;
    if (lane == 0) wsum[wv] = acc;
    __syncthreads();
    if (t == 0) atomicAdd(out, (wsum[0] + wsum[1]) + (wsum[2] + wsum[3]));
}

extern "C" void kernel_launch(void* const* d_in, const int* in_sizes, int n_in,
                              void* d_out, int out_size, void* d_ws, size_t ws_size,
                              hipStream_t stream)
{
    (void)in_sizes; (void)n_in; (void)out_size; (void)ws_size;
    const float* nodes = (const float*)d_in[0];
    const float* W1   = (const float*)d_in[1];
    const float* b1   = (const float*)d_in[2];
    const float* W2   = (const float*)d_in[3];
    const float* b2   = (const float*)d_in[4];
    const float* W3   = (const float*)d_in[5];
    const float* b3   = (const float*)d_in[6];
    const float* W4   = (const float*)d_in[7];
    const float* b4   = (const float*)d_in[8];
    const float* Ixx  = (const float*)d_in[9];
    const float* Iyy  = (const float*)d_in[10];
    const float* B_DD = (const float*)d_in[11];
    const float* wq   = (const float*)d_in[12];
    const float* Base = (const float*)d_in[13];
    const float* J    = (const float*)d_in[14];
    const float* F    = (const float*)d_in[15];
    float* out = (float*)d_out;
    float* evc = (float*)d_ws;                                    // 2048*72 f32
    float* Mc  = (float*)((char*)d_ws + EN * 72 * sizeof(float)); // 256*15*72 f32

    prep_kernel<<<MLP_BLOCKS + MC_BLOCKS, 256, 0, stream>>>(
        nodes, W1, b1, W2, b2, W3, b3, W4, b4, B_DD, Ixx, Iyy, wq, Base,
        evc, Mc, out);
    loss_kernel<<<2048, 256, 0, stream>>>(Mc, evc, J, F, out);
}

// Round 3
// 154.120 us; speedup vs baseline: 1.1550x; 1.1199x over previous
//
#include <hip/hip_runtime.h>

#define EN 2048
#define SN 256
#define QN 25
#define NNODES 36
#define RN 15
#define HN 128
#define KP 96          // K=72 zero-padded to 96 for 3x k32 MFMA steps
#define NTOT (SN * RN) // 3840

typedef __attribute__((ext_vector_type(8))) short short8;
typedef __attribute__((ext_vector_type(4))) float f32x4;
typedef __attribute__((ext_vector_type(2))) unsigned int uint2v;

__device__ __forceinline__ unsigned short f2bf(float f) {
    unsigned int u = __float_as_uint(f);
    u += 0x7fffu + ((u >> 16) & 1u);   // round-to-nearest-even
    return (unsigned short)(u >> 16);
}
__device__ __forceinline__ float bf2f(unsigned short h) {
    return __uint_as_float(((unsigned int)h) << 16);
}
// tanh(x) = 1 - 2/(exp2(2x*log2e)+1)
__device__ __forceinline__ float fast_tanh(float x) {
    float xs = x * 2.885390082f;
    xs = fminf(fmaxf(xs, -60.f), 60.f);
    float e = __builtin_amdgcn_exp2f(xs);
    float r = __builtin_amdgcn_rcpf(e + 1.f);
    return fmaf(-2.f, r, 1.f);
}

// ---------------- MLP helpers (validated in R1/R2) -------------------------
__device__ __forceinline__ void load_W(const float* __restrict__ W,
                                       unsigned short (*Ws)[136], int t)
{
    const int n = t & 127;
    const int h = t >> 7;
    #pragma unroll
    for (int kk = 0; kk < 16; kk++) {
        const int k0 = (kk * 2 + h) * 4;
        const float a0 = W[(k0 + 0) * HN + n];
        const float a1 = W[(k0 + 1) * HN + n];
        const float a2 = W[(k0 + 2) * HN + n];
        const float a3 = W[(k0 + 3) * HN + n];
        uint2v pk;
        pk[0] = (unsigned)f2bf(a0) | ((unsigned)f2bf(a1) << 16);
        pk[1] = (unsigned)f2bf(a2) | ((unsigned)f2bf(a3) << 16);
        *(uint2v*)&Ws[n][k0] = pk;
    }
}

__device__ __forceinline__ void mfma_layer(unsigned short (*Hs)[136],
                                           const unsigned short (*Ws)[136],
                                           const float* __restrict__ bias,
                                           int wv, int rowA, int quad)
{
    const int r0 = wv * 32;               // wave owns 32 rows: no barriers needed
    short8 afrag[2][4];
    #pragma unroll
    for (int rt = 0; rt < 2; rt++)
        #pragma unroll
        for (int kt = 0; kt < 4; kt++)
            afrag[rt][kt] = *(const short8*)&Hs[r0 + rt * 16 + rowA][kt * 32 + quad * 8];

    f32x4 acc[2][8];
    const f32x4 zero = {0.f, 0.f, 0.f, 0.f};
    #pragma unroll
    for (int rt = 0; rt < 2; rt++)
        #pragma unroll
        for (int nt = 0; nt < 8; nt++) acc[rt][nt] = zero;

    #pragma unroll
    for (int nt = 0; nt < 8; nt++) {
        #pragma unroll
        for (int kt = 0; kt < 4; kt++) {
            const short8 bfrag = *(const short8*)&Ws[nt * 16 + rowA][kt * 32 + quad * 8];
            acc[0][nt] = __builtin_amdgcn_mfma_f32_16x16x32_bf16(afrag[0][kt], bfrag, acc[0][nt], 0, 0, 0);
            acc[1][nt] = __builtin_amdgcn_mfma_f32_16x16x32_bf16(afrag[1][kt], bfrag, acc[1][nt], 0, 0, 0);
        }
    }
    #pragma unroll
    for (int nt = 0; nt < 8; nt++) {
        const int col = nt * 16 + rowA;
        const float bv = bias[col];
        #pragma unroll
        for (int rt = 0; rt < 2; rt++) {
            #pragma unroll
            for (int rg = 0; rg < 4; rg++) {
                const float v = fast_tanh(acc[rt][nt][rg] + bv);
                Hs[r0 + rt * 16 + quad * 4 + rg][col] = f2bf(v);
            }
        }
    }
}

// ---------------- fused prep: out-zero + Mcb(bf16) + MLP -> evcb(bf16) -----
#define MLP_BLOCKS 576
#define MC_BLOCKS 1440   // 3840 rows x 96 cols = 368640 = 1440*256

__global__ __launch_bounds__(256, 2)
void prep_kernel(const float* __restrict__ nodes,
                 const float* __restrict__ W1, const float* __restrict__ b1,
                 const float* __restrict__ W2, const float* __restrict__ b2,
                 const float* __restrict__ W3, const float* __restrict__ b3,
                 const float* __restrict__ W4, const float* __restrict__ b4,
                 const float* __restrict__ B_DD,
                 const float* __restrict__ Ixx, const float* __restrict__ Iyy,
                 const float* __restrict__ wq, const float* __restrict__ Base,
                 unsigned short* __restrict__ evcb,
                 unsigned short* __restrict__ Mcb,
                 float* __restrict__ out)
{
    __shared__ unsigned short Hs[128][136];
    __shared__ unsigned short Ws[128][136];
    __shared__ float WB[QN * 16];
    const int bid = blockIdx.x;
    const int t   = threadIdx.x;

    if (bid < MLP_BLOCKS) {
        // =========================== MLP part ===========================
        const int lane = t & 63;
        const int wv   = t >> 6;
        const int rowA = lane & 15;
        const int quad = lane >> 4;

        // layer 1
        {
            const int p  = t >> 1;
            const int P  = bid * 128 + p;
            const float x0 = nodes[2 * P], x1 = nodes[2 * P + 1];
            const int n0 = (t & 1) * 64;
            #pragma unroll
            for (int i = 0; i < 16; i++) {
                const int n = n0 + 4 * i;
                const float4 wa = *(const float4*)(W1 + n);
                const float4 wb = *(const float4*)(W1 + HN + n);
                const float4 bb = *(const float4*)(b1 + n);
                const float h0 = fast_tanh(fmaf(x0, wa.x, fmaf(x1, wb.x, bb.x)));
                const float h1 = fast_tanh(fmaf(x0, wa.y, fmaf(x1, wb.y, bb.y)));
                const float h2 = fast_tanh(fmaf(x0, wa.z, fmaf(x1, wb.z, bb.z)));
                const float h3 = fast_tanh(fmaf(x0, wa.w, fmaf(x1, wb.w, bb.w)));
                uint2v pk;
                pk[0] = (unsigned)f2bf(h0) | ((unsigned)f2bf(h1) << 16);
                pk[1] = (unsigned)f2bf(h2) | ((unsigned)f2bf(h3) << 16);
                *(uint2v*)&Hs[p][n] = pk;
            }
        }
        load_W(W2, Ws, t);
        __syncthreads();
        mfma_layer(Hs, Ws, b2, wv, rowA, quad);
        __syncthreads();
        load_W(W3, Ws, t);
        __syncthreads();
        mfma_layer(Hs, Ws, b3, wv, rowA, quad);
        // layer 4 + evcb epilogue (bf16, K-padded)
        {
            const int p  = t >> 1;
            const int k0 = (t & 1) * 64;
            float d = 0.f;
            #pragma unroll
            for (int i = 0; i < 8; i++) {
                const short8 h = *(const short8*)&Hs[p][k0 + 8 * i];
                const float4 wA = *(const float4*)(W4 + k0 + 8 * i);
                const float4 wB = *(const float4*)(W4 + k0 + 8 * i + 4);
                d = fmaf(bf2f((unsigned short)h[0]), wA.x, d);
                d = fmaf(bf2f((unsigned short)h[1]), wA.y, d);
                d = fmaf(bf2f((unsigned short)h[2]), wA.z, d);
                d = fmaf(bf2f((unsigned short)h[3]), wA.w, d);
                d = fmaf(bf2f((unsigned short)h[4]), wB.x, d);
                d = fmaf(bf2f((unsigned short)h[5]), wB.y, d);
                d = fmaf(bf2f((unsigned short)h[6]), wB.z, d);
                d = fmaf(bf2f((unsigned short)h[7]), wB.w, d);
            }
            d += __shfl_xor(d, 1, 64);
            if ((t & 1) == 0) {
                const float ev = d + b4[0];
                const int P  = bid * 128 + p;
                const int e  = P / NNODES;
                const int ne = P - e * NNODES;
                const float c0 = B_DD[4 * e + 0] + B_DD[4 * e + 2];
                const float c1 = B_DD[4 * e + 1] + B_DD[4 * e + 3];
                evcb[e * KP + ne]          = f2bf(c0 * ev);
                evcb[e * KP + NNODES + ne] = f2bf(c1 * ev);
                if (ne < KP - 2 * NNODES)              // zero the 24-pad
                    evcb[e * KP + 2 * NNODES + ne] = 0;
            }
        }
    } else {
        // =========================== Mcb part ===========================
        if (bid == MLP_BLOCKS && t == 0) out[0] = 0.f;
        for (int i = t; i < QN * 16; i += 256) {
            const int q = i >> 4, r = i & 15;
            if (r < RN) WB[i] = wq[q] * Base[q * RN + r];
        }
        __syncthreads();
        const int o = (bid - MLP_BLOCKS) * 256 + t;   // covers 3840*96 exactly
        const int c = o % KP;
        const int n = o / KP;                          // n = s*15 + r
        if (c >= 2 * NNODES) { Mcb[o] = 0; return; }   // zero-pad k 72..95
        const int r = n % RN;
        const int s = n / RN;
        const float* __restrict__ I = (c < NNODES) ? Ixx : Iyy;
        const int cn = (c < NNODES) ? c : (c - NNODES);
        float a0 = 0.f, a1 = 0.f;
        #pragma unroll
        for (int q = 0; q < QN - 1; q += 2) {
            a0 = fmaf(WB[q * 16 + r],       I[(s * QN + q) * NNODES + cn],     a0);
            a1 = fmaf(WB[(q + 1) * 16 + r], I[(s * QN + q + 1) * NNODES + cn], a1);
        }
        a0 = fmaf(WB[(QN - 1) * 16 + r], I[(s * QN + QN - 1) * NNODES + cn], a0);
        Mcb[o] = f2bf(a0 + a1);
    }
}

// ---------------- loss: bf16 MFMA GEMM U = evcb @ Mcb^T + fused epilogue ---
// grid: 32 m-blocks (64 e) x 30 n-blocks (128 n). Block = 4 waves; wave wv
// handles the full 64 m rows x 32 n cols (nt 0..1).
__global__ __launch_bounds__(256, 4)
void loss_kernel(const unsigned short* __restrict__ evcb,
                 const unsigned short* __restrict__ Mcb,
                 const float* __restrict__ J, const float* __restrict__ F,
                 float* __restrict__ out)
{
    const int t    = threadIdx.x;
    const int lane = t & 63;
    const int wv   = t >> 6;
    const int rowA = lane & 15;
    const int quad = lane >> 4;
    const int m0 = (blockIdx.x & 31) * 64;
    const int n0 = (blockIdx.x >> 5) * 128 + wv * 32;

    f32x4 acc[4][2];
    const f32x4 zero = {0.f, 0.f, 0.f, 0.f};
    #pragma unroll
    for (int mt = 0; mt < 4; mt++)
        #pragma unroll
        for (int nt = 0; nt < 2; nt++) acc[mt][nt] = zero;

    #pragma unroll
    for (int kt = 0; kt < 3; kt++) {
        short8 a[4], b[2];
        #pragma unroll
        for (int mt = 0; mt < 4; mt++)
            a[mt] = *(const short8*)&evcb[(m0 + mt * 16 + rowA) * KP + kt * 32 + quad * 8];
        #pragma unroll
        for (int nt = 0; nt < 2; nt++)
            b[nt] = *(const short8*)&Mcb[(n0 + nt * 16 + rowA) * KP + kt * 32 + quad * 8];
        #pragma unroll
        for (int mt = 0; mt < 4; mt++)
            #pragma unroll
            for (int nt = 0; nt < 2; nt++)
                acc[mt][nt] = __builtin_amdgcn_mfma_f32_16x16x32_bf16(a[mt], b[nt], acc[mt][nt], 0, 0, 0);
    }

    // epilogue: res = -J*d - F; accumulate res^2/15 (flat sum == sum of means)
    float total = 0.f;
    #pragma unroll
    for (int nt = 0; nt < 2; nt++) {
        const int n = n0 + nt * 16 + rowA;
        const int s = (n * 34953) >> 19;               // n/15 for n<3840
        #pragma unroll
        for (int mt = 0; mt < 4; mt++) {
            const int eb = m0 + mt * 16 + quad * 4;
            #pragma unroll
            for (int rg = 0; rg < 4; rg++) {
                const int e = eb + rg;
                const float Jv = J[e * SN + s];
                const float Fv = F[e * NTOT + n];
                const float d  = acc[mt][nt][rg];
                const float res = fmaf(-Jv, d, -Fv);
                total = fmaf(res, res, total);
            }
        }
    }
    total *= (1.f / (float)RN);

    #pragma unroll
    for (int off = 32; off; off >>= 1)
        total += __shfl_down(total, off, 64);
    __shared__ float wsum[4];
    if (lane == 0) wsum[wv] = total;
    __syncthreads();
    if (t == 0) atomicAdd(out, (wsum[0] + wsum[1]) + (wsum[2] + wsum[3]));
}

extern "C" void kernel_launch(void* const* d_in, const int* in_sizes, int n_in,
                              void* d_out, int out_size, void* d_ws, size_t ws_size,
                              hipStream_t stream)
{
    (void)in_sizes; (void)n_in; (void)out_size; (void)ws_size;
    const float* nodes = (const float*)d_in[0];
    const float* W1   = (const float*)d_in[1];
    const float* b1   = (const float*)d_in[2];
    const float* W2   = (const float*)d_in[3];
    const float* b2   = (const float*)d_in[4];
    const float* W3   = (const float*)d_in[5];
    const float* b3   = (const float*)d_in[6];
    const float* W4   = (const float*)d_in[7];
    const float* b4   = (const float*)d_in[8];
    const float* Ixx  = (const float*)d_in[9];
    const float* Iyy  = (const float*)d_in[10];
    const float* B_DD = (const float*)d_in[11];
    const float* wq   = (const float*)d_in[12];
    const float* Base = (const float*)d_in[13];
    const float* J    = (const float*)d_in[14];
    const float* F    = (const float*)d_in[15];
    float* out = (float*)d_out;
    unsigned short* evcb = (unsigned short*)d_ws;                    // 2048*96 bf16
    unsigned short* Mcb  = (unsigned short*)((char*)d_ws + EN * KP * 2); // 3840*96 bf16

    prep_kernel<<<MLP_BLOCKS + MC_BLOCKS, 256, 0, stream>>>(
        nodes, W1, b1, W2, b2, W3, b3, W4, b4, B_DD, Ixx, Iyy, wq, Base,
        evcb, Mcb, out);
    loss_kernel<<<32 * 30, 256, 0, stream>>>(evcb, Mcb, J, F, out);
}

// Round 4
// 143.938 us; speedup vs baseline: 1.2367x; 1.0707x over previous
//
#include <hip/hip_runtime.h>

#define EN 2048
#define SN 256
#define QN 25
#define NNODES 36
#define RN 15
#define HN 128
#define KP 96          // K=72 zero-padded to 96 for 3x k32 MFMA steps
#define NTOT (SN * RN) // 3840

typedef __attribute__((ext_vector_type(8))) short short8;
typedef __attribute__((ext_vector_type(4))) float f32x4;
typedef __attribute__((ext_vector_type(2))) unsigned int uint2v;

__device__ __forceinline__ unsigned short f2bf(float f) {
    unsigned int u = __float_as_uint(f);
    u += 0x7fffu + ((u >> 16) & 1u);   // round-to-nearest-even
    return (unsigned short)(u >> 16);
}
__device__ __forceinline__ float bf2f(unsigned short h) {
    return __uint_as_float(((unsigned int)h) << 16);
}
// tanh(x) = 1 - 2/(exp2(2x*log2e)+1)
__device__ __forceinline__ float fast_tanh(float x) {
    float xs = x * 2.885390082f;
    xs = fminf(fmaxf(xs, -60.f), 60.f);
    float e = __builtin_amdgcn_exp2f(xs);
    float r = __builtin_amdgcn_rcpf(e + 1.f);
    return fmaf(-2.f, r, 1.f);
}

// ---------------- MLP helpers (validated R1-R3) ----------------------------
__device__ __forceinline__ void load_W(const float* __restrict__ W,
                                       unsigned short (*Ws)[136], int t)
{
    const int n = t & 127;
    const int h = t >> 7;
    #pragma unroll
    for (int kk = 0; kk < 16; kk++) {
        const int k0 = (kk * 2 + h) * 4;
        const float a0 = W[(k0 + 0) * HN + n];
        const float a1 = W[(k0 + 1) * HN + n];
        const float a2 = W[(k0 + 2) * HN + n];
        const float a3 = W[(k0 + 3) * HN + n];
        uint2v pk;
        pk[0] = (unsigned)f2bf(a0) | ((unsigned)f2bf(a1) << 16);
        pk[1] = (unsigned)f2bf(a2) | ((unsigned)f2bf(a3) << 16);
        *(uint2v*)&Ws[n][k0] = pk;
    }
}

__device__ __forceinline__ void mfma_layer(unsigned short (*Hs)[136],
                                           const unsigned short (*Ws)[136],
                                           const float* __restrict__ bias,
                                           int wv, int rowA, int quad)
{
    const int r0 = wv * 32;               // wave owns 32 rows: no barriers needed
    short8 afrag[2][4];
    #pragma unroll
    for (int rt = 0; rt < 2; rt++)
        #pragma unroll
        for (int kt = 0; kt < 4; kt++)
            afrag[rt][kt] = *(const short8*)&Hs[r0 + rt * 16 + rowA][kt * 32 + quad * 8];

    f32x4 acc[2][8];
    const f32x4 zero = {0.f, 0.f, 0.f, 0.f};
    #pragma unroll
    for (int rt = 0; rt < 2; rt++)
        #pragma unroll
        for (int nt = 0; nt < 8; nt++) acc[rt][nt] = zero;

    #pragma unroll
    for (int nt = 0; nt < 8; nt++) {
        #pragma unroll
        for (int kt = 0; kt < 4; kt++) {
            const short8 bfrag = *(const short8*)&Ws[nt * 16 + rowA][kt * 32 + quad * 8];
            acc[0][nt] = __builtin_amdgcn_mfma_f32_16x16x32_bf16(afrag[0][kt], bfrag, acc[0][nt], 0, 0, 0);
            acc[1][nt] = __builtin_amdgcn_mfma_f32_16x16x32_bf16(afrag[1][kt], bfrag, acc[1][nt], 0, 0, 0);
        }
    }
    #pragma unroll
    for (int nt = 0; nt < 8; nt++) {
        const int col = nt * 16 + rowA;
        const float bv = bias[col];
        #pragma unroll
        for (int rt = 0; rt < 2; rt++) {
            #pragma unroll
            for (int rg = 0; rg < 4; rg++) {
                const float v = fast_tanh(acc[rt][nt][rg] + bv);
                Hs[r0 + rt * 16 + quad * 4 + rg][col] = f2bf(v);
            }
        }
    }
}

// ---------------- fused prep: out-zero + Mcb(bf16, LDS-staged) + MLP -------
#define MLP_BLOCKS 576
#define MC_BLOCKS  SN    // one block per sub-element s

__global__ __launch_bounds__(256, 2)
void prep_kernel(const float* __restrict__ nodes,
                 const float* __restrict__ W1, const float* __restrict__ b1,
                 const float* __restrict__ W2, const float* __restrict__ b2,
                 const float* __restrict__ W3, const float* __restrict__ b3,
                 const float* __restrict__ W4, const float* __restrict__ b4,
                 const float* __restrict__ B_DD,
                 const float* __restrict__ Ixx, const float* __restrict__ Iyy,
                 const float* __restrict__ wq, const float* __restrict__ Base,
                 unsigned short* __restrict__ evcb,
                 unsigned short* __restrict__ Mcb,
                 float* __restrict__ out)
{
    __shared__ unsigned short Hs[128][136];
    __shared__ unsigned short Ws[128][136];
    __shared__ float WB[QN * 16];
    const int bid = blockIdx.x;
    const int t   = threadIdx.x;

    if (bid < MLP_BLOCKS) {
        // =========================== MLP part ===========================
        const int lane = t & 63;
        const int wv   = t >> 6;
        const int rowA = lane & 15;
        const int quad = lane >> 4;

        // layer 1
        {
            const int p  = t >> 1;
            const int P  = bid * 128 + p;
            const float x0 = nodes[2 * P], x1 = nodes[2 * P + 1];
            const int n0 = (t & 1) * 64;
            #pragma unroll
            for (int i = 0; i < 16; i++) {
                const int n = n0 + 4 * i;
                const float4 wa = *(const float4*)(W1 + n);
                const float4 wb = *(const float4*)(W1 + HN + n);
                const float4 bb = *(const float4*)(b1 + n);
                const float h0 = fast_tanh(fmaf(x0, wa.x, fmaf(x1, wb.x, bb.x)));
                const float h1 = fast_tanh(fmaf(x0, wa.y, fmaf(x1, wb.y, bb.y)));
                const float h2 = fast_tanh(fmaf(x0, wa.z, fmaf(x1, wb.z, bb.z)));
                const float h3 = fast_tanh(fmaf(x0, wa.w, fmaf(x1, wb.w, bb.w)));
                uint2v pk;
                pk[0] = (unsigned)f2bf(h0) | ((unsigned)f2bf(h1) << 16);
                pk[1] = (unsigned)f2bf(h2) | ((unsigned)f2bf(h3) << 16);
                *(uint2v*)&Hs[p][n] = pk;
            }
        }
        load_W(W2, Ws, t);
        __syncthreads();
        mfma_layer(Hs, Ws, b2, wv, rowA, quad);
        __syncthreads();
        load_W(W3, Ws, t);
        __syncthreads();
        mfma_layer(Hs, Ws, b3, wv, rowA, quad);
        // layer 4 + evcb epilogue (bf16, K-padded)
        {
            const int p  = t >> 1;
            const int k0 = (t & 1) * 64;
            float d = 0.f;
            #pragma unroll
            for (int i = 0; i < 8; i++) {
                const short8 h = *(const short8*)&Hs[p][k0 + 8 * i];
                const float4 wA = *(const float4*)(W4 + k0 + 8 * i);
                const float4 wB = *(const float4*)(W4 + k0 + 8 * i + 4);
                d = fmaf(bf2f((unsigned short)h[0]), wA.x, d);
                d = fmaf(bf2f((unsigned short)h[1]), wA.y, d);
                d = fmaf(bf2f((unsigned short)h[2]), wA.z, d);
                d = fmaf(bf2f((unsigned short)h[3]), wA.w, d);
                d = fmaf(bf2f((unsigned short)h[4]), wB.x, d);
                d = fmaf(bf2f((unsigned short)h[5]), wB.y, d);
                d = fmaf(bf2f((unsigned short)h[6]), wB.z, d);
                d = fmaf(bf2f((unsigned short)h[7]), wB.w, d);
            }
            d += __shfl_xor(d, 1, 64);
            if ((t & 1) == 0) {
                const float ev = d + b4[0];
                const int P  = bid * 128 + p;
                const int e  = P / NNODES;
                const int ne = P - e * NNODES;
                const float c0 = B_DD[4 * e + 0] + B_DD[4 * e + 2];
                const float c1 = B_DD[4 * e + 1] + B_DD[4 * e + 3];
                evcb[e * KP + ne]          = f2bf(c0 * ev);
                evcb[e * KP + NNODES + ne] = f2bf(c1 * ev);
                if (ne < KP - 2 * NNODES)              // zero the 24-pad
                    evcb[e * KP + 2 * NNODES + ne] = 0;
            }
        }
    } else {
        // ============== Mcb part: one block per s, LDS-staged ===========
        const int s = bid - MLP_BLOCKS;           // 0..255
        if (s == 0 && t == 0) out[0] = 0.f;
        float* I_lds = (float*)&Hs[0][0];         // 1800 f32, aliases Hs
        for (int i = t; i < QN * 16; i += 256) {
            const int q = i >> 4, r = i & 15;
            if (r < RN) WB[i] = wq[q] * Base[q * RN + r];
        }
        const float* __restrict__ Ia = Ixx + (size_t)s * (QN * NNODES);
        const float* __restrict__ Ib = Iyy + (size_t)s * (QN * NNODES);
        for (int i = t; i < QN * NNODES; i += 256) {
            I_lds[i]               = Ia[i];
            I_lds[QN * NNODES + i] = Ib[i];
        }
        __syncthreads();
        // 15 r x 96 c outputs = 1440, 256 threads -> 6 strided iterations
        for (int o = t; o < RN * KP; o += 256) {
            const int c = o % KP;
            const int r = o / KP;
            float v = 0.f;
            if (c < 2 * NNODES) {
                const float* __restrict__ Ip =
                    I_lds + ((c < NNODES) ? c : (QN * NNODES + c - NNODES));
                float a0 = 0.f, a1 = 0.f;
                #pragma unroll
                for (int q = 0; q < QN - 1; q += 2) {
                    a0 = fmaf(WB[q * 16 + r],       Ip[q * NNODES],       a0);
                    a1 = fmaf(WB[(q + 1) * 16 + r], Ip[(q + 1) * NNODES], a1);
                }
                a0 = fmaf(WB[(QN - 1) * 16 + r], Ip[(QN - 1) * NNODES], a0);
                v = a0 + a1;
            }
            Mcb[((size_t)s * RN + r) * KP + c] = f2bf(v);
        }
    }
}

// ---------------- loss: bf16 MFMA GEMM + F-prefetch + fused epilogue -------
__global__ __launch_bounds__(256, 4)
void loss_kernel(const unsigned short* __restrict__ evcb,
                 const unsigned short* __restrict__ Mcb,
                 const float* __restrict__ J, const float* __restrict__ F,
                 float* __restrict__ out)
{
    const int t    = threadIdx.x;
    const int lane = t & 63;
    const int wv   = t >> 6;
    const int rowA = lane & 15;
    const int quad = lane >> 4;
    const int m0 = (blockIdx.x & 31) * 64;
    const int n0 = (blockIdx.x >> 5) * 128 + wv * 32;

    // prefetch F (the only HBM stream) before the GEMM: 32 loads in flight
    float Fv[2][16];
    #pragma unroll
    for (int nt = 0; nt < 2; nt++) {
        const int n = n0 + nt * 16 + rowA;
        #pragma unroll
        for (int mt = 0; mt < 4; mt++)
            #pragma unroll
            for (int rg = 0; rg < 4; rg++)
                Fv[nt][mt * 4 + rg] = F[(size_t)(m0 + mt * 16 + quad * 4 + rg) * NTOT + n];
    }

    f32x4 acc[4][2];
    const f32x4 zero = {0.f, 0.f, 0.f, 0.f};
    #pragma unroll
    for (int mt = 0; mt < 4; mt++)
        #pragma unroll
        for (int nt = 0; nt < 2; nt++) acc[mt][nt] = zero;

    #pragma unroll
    for (int kt = 0; kt < 3; kt++) {
        short8 a[4], b[2];
        #pragma unroll
        for (int mt = 0; mt < 4; mt++)
            a[mt] = *(const short8*)&evcb[(size_t)(m0 + mt * 16 + rowA) * KP + kt * 32 + quad * 8];
        #pragma unroll
        for (int nt = 0; nt < 2; nt++)
            b[nt] = *(const short8*)&Mcb[(size_t)(n0 + nt * 16 + rowA) * KP + kt * 32 + quad * 8];
        #pragma unroll
        for (int mt = 0; mt < 4; mt++)
            #pragma unroll
            for (int nt = 0; nt < 2; nt++)
                acc[mt][nt] = __builtin_amdgcn_mfma_f32_16x16x32_bf16(a[mt], b[nt], acc[mt][nt], 0, 0, 0);
    }

    // epilogue: res = -J*d - F; accumulate res^2/15 (flat sum == sum of means)
    float total = 0.f;
    #pragma unroll
    for (int nt = 0; nt < 2; nt++) {
        const int n = n0 + nt * 16 + rowA;
        const int s = (n * 34953) >> 19;               // n/15 for n<3840
        #pragma unroll
        for (int mt = 0; mt < 4; mt++) {
            const int eb = m0 + mt * 16 + quad * 4;
            #pragma unroll
            for (int rg = 0; rg < 4; rg++) {
                const float Jv = J[(size_t)(eb + rg) * SN + s];
                const float d  = acc[mt][nt][rg];
                const float res = fmaf(-Jv, d, -Fv[nt][mt * 4 + rg]);
                total = fmaf(res, res, total);
            }
        }
    }
    total *= (1.f / (float)RN);

    #pragma unroll
    for (int off = 32; off; off >>= 1)
        total += __shfl_down(total, off, 64);
    __shared__ float wsum[4];
    if (lane == 0) wsum[wv] = total;
    __syncthreads();
    if (t == 0) atomicAdd(out, (wsum[0] + wsum[1]) + (wsum[2] + wsum[3]));
}

extern "C" void kernel_launch(void* const* d_in, const int* in_sizes, int n_in,
                              void* d_out, int out_size, void* d_ws, size_t ws_size,
                              hipStream_t stream)
{
    (void)in_sizes; (void)n_in; (void)out_size; (void)ws_size;
    const float* nodes = (const float*)d_in[0];
    const float* W1   = (const float*)d_in[1];
    const float* b1   = (const float*)d_in[2];
    const float* W2   = (const float*)d_in[3];
    const float* b2   = (const float*)d_in[4];
    const float* W3   = (const float*)d_in[5];
    const float* b3   = (const float*)d_in[6];
    const float* W4   = (const float*)d_in[7];
    const float* b4   = (const float*)d_in[8];
    const float* Ixx  = (const float*)d_in[9];
    const float* Iyy  = (const float*)d_in[10];
    const float* B_DD = (const float*)d_in[11];
    const float* wq   = (const float*)d_in[12];
    const float* Base = (const float*)d_in[13];
    const float* J    = (const float*)d_in[14];
    const float* F    = (const float*)d_in[15];
    float* out = (float*)d_out;
    unsigned short* evcb = (unsigned short*)d_ws;                        // 2048*96 bf16
    unsigned short* Mcb  = (unsigned short*)((char*)d_ws + EN * KP * 2); // 3840*96 bf16

    prep_kernel<<<MLP_BLOCKS + MC_BLOCKS, 256, 0, stream>>>(
        nodes, W1, b1, W2, b2, W3, b3, W4, b4, B_DD, Ixx, Iyy, wq, Base,
        evcb, Mcb, out);
    loss_kernel<<<32 * 30, 256, 0, stream>>>(evcb, Mcb, J, F, out);
}